// Round 3
// baseline (1715.714 us; speedup 1.0000x reference)
//
#include <hip/hip_runtime.h>
#include <hip/hip_bf16.h>

#define LL 768
#define TOPK 128

// workspace layout (floats)
#define WS_SEQ  0                       // 768*256
#define WS_NODE (WS_SEQ + LL*256)       // 768*32
#define WS_NBR  (WS_NODE + LL*32)       // 768*128 ints
#define WS_SOUT (WS_NBR + LL*TOPK)      // 768*16
#define WS_COL  (WS_SOUT + LL*16)       // 32

#define FMA_ROW32(ACC, XVAL, WPTR) do {                                   \
    const float _x = (XVAL);                                              \
    const float* __restrict__ _w = (WPTR);                                \
    _Pragma("unroll")                                                     \
    for (int _c = 0; _c < 32; ++_c) ACC[_c] = fmaf(_x, _w[_c], ACC[_c]);  \
  } while (0)

#define LN32(DST, SRC) do {                                               \
    float _m = 0.f;                                                       \
    _Pragma("unroll")                                                     \
    for (int _c = 0; _c < 32; ++_c) _m += SRC[_c];                        \
    _m *= (1.f/32.f);                                                     \
    float _v = 0.f;                                                       \
    _Pragma("unroll")                                                     \
    for (int _c = 0; _c < 32; ++_c) { float _d = SRC[_c]-_m; _v += _d*_d; } \
    _v *= (1.f/32.f);                                                     \
    float _rs = 1.f / sqrtf(_v + 1e-5f);                                  \
    _Pragma("unroll")                                                     \
    for (int _c = 0; _c < 32; ++_c) DST[_c] = (SRC[_c]-_m)*_rs;           \
  } while (0)

__device__ __forceinline__ float block_sum_256(float v, float* red, int t) {
#pragma unroll
  for (int o = 32; o > 0; o >>= 1) v += __shfl_xor(v, o, 64);
  __syncthreads();
  if ((t & 63) == 0) red[t >> 6] = v;
  __syncthreads();
  return red[0] + red[1] + red[2] + red[3];
}

// ---------------- Kernel P: column sums of W_ee pair-part (128x32) ---------
__global__ void kernP(const float* __restrict__ W_ee, float* __restrict__ colsum)
{
  const int c = threadIdx.x;   // 32 threads
  float s = 0.f;
  for (int k = 0; k < 128; ++k) s += W_ee[k*32 + c];
  colsum[c] = s;
}

// ---------------- Kernel A: seq LN, state LN, node MLP + LN ----------------
__global__ __launch_bounds__(256) void kernA(
    const float* __restrict__ msa, const float* __restrict__ state,
    const float* __restrict__ W_en, const float* __restrict__ b_en,
    const float* __restrict__ Wn1, const float* __restrict__ bn1,
    const float* __restrict__ Wn2, const float* __restrict__ bn2,
    float* __restrict__ seq_ln, float* __restrict__ nodeo)
{
  const int i = blockIdx.x, t = threadIdx.x;
  __shared__ float x[256];
  __shared__ float red[4];
  __shared__ float sn[16], n0[32], tn[32], hh[64], n1v[32];

  float v = msa[i*256 + t];
  float mean = block_sum_256(v, red, t) * (1.f/256.f);
  float d = v - mean;
  float var = block_sum_256(d*d, red, t) * (1.f/256.f);
  float xn = d / sqrtf(var + 1e-5f);
  x[t] = xn;
  seq_ln[i*256 + t] = xn;

  if (t < 16) {
    float m2 = 0.f;
    for (int k = 0; k < 16; ++k) m2 += state[i*16 + k];
    m2 *= (1.f/16.f);
    float v2 = 0.f;
    for (int k = 0; k < 16; ++k) { float dd = state[i*16 + k] - m2; v2 += dd*dd; }
    v2 *= (1.f/16.f);
    sn[t] = (state[i*16 + t] - m2) / sqrtf(v2 + 1e-5f);
  }
  __syncthreads();

  if (t < 32) {
    float a = b_en[t];
    for (int k = 0; k < 256; ++k) a = fmaf(x[k], W_en[k*32 + t], a);
    for (int k = 0; k < 16; ++k)  a = fmaf(sn[k], W_en[(256+k)*32 + t], a);
    n0[t] = a;
  }
  __syncthreads();
  if (t < 32) {
    float m = 0.f;
    for (int k = 0; k < 32; ++k) m += n0[k];
    m *= (1.f/32.f);
    float vv = 0.f;
    for (int k = 0; k < 32; ++k) { float dd = n0[k] - m; vv += dd*dd; }
    vv *= (1.f/32.f);
    tn[t] = (n0[t] - m) / sqrtf(vv + 1e-5f);
  }
  __syncthreads();
  if (t < 64) {
    float a = bn1[t];
    for (int k = 0; k < 32; ++k) a = fmaf(tn[k], Wn1[k*64 + t], a);
    hh[t] = fmaxf(a, 0.f);
  }
  __syncthreads();
  if (t < 32) {
    float a = n0[t] + bn2[t];
    for (int k = 0; k < 64; ++k) a = fmaf(hh[k], Wn2[k*32 + t], a);
    n1v[t] = a;
  }
  __syncthreads();
  if (t < 32) {
    float m = 0.f;
    for (int k = 0; k < 32; ++k) m += n1v[k];
    m *= (1.f/32.f);
    float vv = 0.f;
    for (int k = 0; k < 32; ++k) { float dd = n1v[k] - m; vv += dd*dd; }
    vv *= (1.f/32.f);
    nodeo[i*32 + t] = (n1v[t] - m) / sqrtf(vv + 1e-5f);
  }
}

// ---------------- Kernel B: top-128 nearest by D, bitonic (D_bits, j) -------
__global__ __launch_bounds__(256) void kernB(const float* __restrict__ xyz,
                                             int* __restrict__ nbr)
{
  const int i = blockIdx.x, t = threadIdx.x;
  __shared__ unsigned long long keys[1024];
  const float cix = xyz[i*9+3], ciy = xyz[i*9+4], ciz = xyz[i*9+5];

  for (int j = t; j < 1024; j += 256) {
    unsigned long long kk = ~0ull;
    if (j < LL) {
      float dx = __fadd_rn(cix, -xyz[j*9+3]);
      float dy = __fadd_rn(ciy, -xyz[j*9+4]);
      float dz = __fadd_rn(ciz, -xyz[j*9+5]);
      float Dv = sqrtf(__fadd_rn(__fadd_rn(__fadd_rn(__fmul_rn(dx,dx),
                         __fmul_rn(dy,dy)), __fmul_rn(dz,dz)), 1e-8f));
      kk = (((unsigned long long)__float_as_uint(Dv)) << 32) | (unsigned)j;
    }
    keys[j] = kk;
  }
  for (int size = 2; size <= 1024; size <<= 1) {
    for (int stride = size >> 1; stride > 0; stride >>= 1) {
      __syncthreads();
      for (int p = t; p < 512; p += 256) {
        int lo = 2*p - (p & (stride - 1));
        int hi = lo + stride;
        bool up = ((lo & size) == 0);
        unsigned long long a = keys[lo], b = keys[hi];
        if ((a > b) == up) { keys[lo] = b; keys[hi] = a; }
      }
    }
  }
  __syncthreads();
  if (t < TOPK) nbr[i*TOPK + t] = (int)(keys[t] & 0xffffffffu);
}

// ---------------- Kernel C: edge+message pipeline, 2 lanes per neighbor ----
// lane pair (l, l^32) within a wave handles one neighbor; 256 thr = 128 nbrs.
__global__ __launch_bounds__(256, 3) void kernC(
    const float* __restrict__ pair, const float* __restrict__ xyz,
    const int* __restrict__ idx, const unsigned char* __restrict__ rmask,
    const float* __restrict__ W_ee, const float* __restrict__ b_ee,
    const float* __restrict__ We1, const float* __restrict__ be1,
    const float* __restrict__ We2, const float* __restrict__ be2,
    const float* __restrict__ Wm1, const float* __restrict__ bm1,
    const float* __restrict__ Wm2, const float* __restrict__ bm2,
    const float* __restrict__ Wl0, const float* __restrict__ bl0,
    const float* __restrict__ node, const int* __restrict__ nbr,
    const float* __restrict__ colsum,
    float* __restrict__ soutf, float* __restrict__ out)
{
  const int i = blockIdx.x, t = threadIdx.x;
  const int lane = t & 63, wv = t >> 6;
  const int p = wv*32 + (lane & 31);   // neighbor slot 0..127
  const int half = lane >> 5;          // 0 or 1
  __shared__ float ni[32];
  __shared__ float red[4][44];
  __shared__ float fin[44];

  if (t < 32) ni[t] = node[i*32 + t];
  __syncthreads();

  const int j = nbr[i*TOPK + p];
  const float cix = xyz[i*9+3], ciy = xyz[i*9+4], ciz = xyz[i*9+5];
  const float cjx = xyz[j*9+3], cjy = xyz[j*9+4], cjz = xyz[j*9+5];
  const float dx = __fadd_rn(cix, -cjx), dy = __fadd_rn(ciy, -cjy), dz = __fadd_rn(ciz, -cjz);
  const float Dv = sqrtf(__fadd_rn(__fadd_rn(__fadd_rn(__fmul_rn(dx,dx),
                      __fmul_rn(dy,dy)), __fmul_rn(dz,dz)), 1e-8f));

  // --- single-pass pair-row: raw matvec + LN stats (this lane's 64 floats) ---
  const float* prow = pair + (((size_t)i*LL + j) * 128) + half*64;
  float acc[32];
#pragma unroll
  for (int c = 0; c < 32; ++c) acc[c] = 0.f;
  float s = 0.f, ss = 0.f;
#pragma unroll 4
  for (int q = 0; q < 16; ++q) {
    float4 v = ((const float4*)prow)[q];
    s  += (v.x + v.y) + (v.z + v.w);
    ss += v.x*v.x + v.y*v.y + v.z*v.z + v.w*v.w;
    const float* wr = W_ee + (half*64 + q*4)*32;
    FMA_ROW32(acc, v.x, wr);
    FMA_ROW32(acc, v.y, wr + 32);
    FMA_ROW32(acc, v.z, wr + 64);
    FMA_ROW32(acc, v.w, wr + 96);
  }
  s  += __shfl_xor(s, 32);
  ss += __shfl_xor(ss, 32);
  const float pm  = s * (1.f/128.f);
  const float pvv = ss * (1.f/128.f) - pm*pm;
  const float prs = 1.f / sqrtf(pvv + 1e-5f);

  float e0[32];
#pragma unroll
  for (int c = 0; c < 32; ++c) e0[c] = prs * acc[c];

  // RBF part, k-split across the pair
#pragma unroll 4
  for (int kk = 0; kk < 32; ++kk) {
    const int k = half*32 + kk;
    float mu = 2.f + (float)k * (20.f/63.f);
    float u  = (Dv - mu) / 0.3125f;
    FMA_ROW32(e0, expf(-(u*u)), W_ee + (128+k)*32);
  }
  if (half == 0) {   // seqsep + bias + LN affine correction (counted once)
    const float offv = (float)(idx[j] - idx[i]);
    const float sg = (offv > 0.f) ? 1.f : ((offv < 0.f) ? -1.f : 0.f);
    const float xsep = sg * logf(fabsf(offv) + 1.f);
    FMA_ROW32(e0, xsep, W_ee + 192*32);
    const float corr = -prs * pm;
#pragma unroll
    for (int c = 0; c < 32; ++c) e0[c] += b_ee[c] + corr * colsum[c];
  }
#pragma unroll
  for (int c = 0; c < 32; ++c) e0[c] += __shfl_xor(e0[c], 32);  // full edge0

  float ed[32];
  LN32(ed, e0);

  // h = relu(ed @ We1 + be1), output-split: this lane owns channels half*32..+32
  float h[32];
  {
    const float* w1 = We1 + half*32;
    const float* b1 = be1 + half*32;
#pragma unroll
    for (int c = 0; c < 32; ++c) h[c] = b1[c];
#pragma unroll
    for (int k = 0; k < 32; ++k) {
      const float xv = ed[k];
      const float* wr = w1 + k*64;
#pragma unroll
      for (int c = 0; c < 32; ++c) h[c] = fmaf(xv, wr[c], h[c]);
    }
#pragma unroll
    for (int c = 0; c < 32; ++c) h[c] = fmaxf(h[c], 0.f);
  }

  // e2 = edge0 + h @ We2 + be2; h is this lane's k-half -> partial, exchange
  float f[32];
#pragma unroll
  for (int c = 0; c < 32; ++c) f[c] = (half == 0) ? (e0[c] + be2[c]) : 0.f;
  {
    const float* w2 = We2 + (half*32)*32;
#pragma unroll
    for (int k = 0; k < 32; ++k) {
      const float xv = h[k];
      const float* wr = w2 + k*32;
#pragma unroll
      for (int c = 0; c < 32; ++c) f[c] = fmaf(xv, wr[c], f[c]);
    }
  }
#pragma unroll
  for (int c = 0; c < 32; ++c) f[c] += __shfl_xor(f[c], 32);  // full e2

  float ed2[32];
  LN32(ed2, f);

  // m1 = relu([ni, hj, ed2] @ Wm1 + bm1), output-split
  float m1[32];
  {
    const float* wm = Wm1 + half*32;
    const float* bb = bm1 + half*32;
#pragma unroll
    for (int c = 0; c < 32; ++c) m1[c] = bb[c];
#pragma unroll 8
    for (int k = 0; k < 32; ++k) {
      const float xv = ni[k];
      const float* wr = wm + k*64;
#pragma unroll
      for (int c = 0; c < 32; ++c) m1[c] = fmaf(xv, wr[c], m1[c]);
    }
    const float* nj = node + j*32;
#pragma unroll 8
    for (int k = 0; k < 32; ++k) {
      const float xv = nj[k];
      const float* wr = wm + (32+k)*64;
#pragma unroll
      for (int c = 0; c < 32; ++c) m1[c] = fmaf(xv, wr[c], m1[c]);
    }
#pragma unroll
    for (int k = 0; k < 32; ++k) {
      const float xv = ed2[k];
      const float* wr = wm + (64+k)*64;
#pragma unroll
      for (int c = 0; c < 32; ++c) m1[c] = fmaf(xv, wr[c], m1[c]);
    }
#pragma unroll
    for (int c = 0; c < 32; ++c) m1[c] = fmaxf(m1[c], 0.f);
  }

  // m2 = m1 @ Wm2 + bm2; m1 is this lane's k-half -> m2 stays a k-partial
  // (legal: everything downstream of m2 is linear in m2 and block-summed)
  float m2[40];
#pragma unroll
  for (int o = 0; o < 40; ++o) m2[o] = (half == 0) ? bm2[o] : 0.f;
  {
    const float* wm = Wm2 + (half*32)*40;
#pragma unroll
    for (int k = 0; k < 32; ++k) {
      const float xv = m1[k];
      const float* wr = wm + k*40;
#pragma unroll
      for (int o = 0; o < 40; ++o) m2[o] = fmaf(xv, wr[o], m2[o]);
    }
  }

  // per-lane contributions -> block reduce (deterministic)
  const float rx = cjx - cix, ry = cjy - ciy, rz = cjz - ciz;
  float contrib[44];
#pragma unroll
  for (int q = 0; q < 32; ++q) contrib[q] = m2[q];
  contrib[32] = m2[32]*rx; contrib[33] = m2[32]*ry; contrib[34] = m2[32]*rz;
  contrib[35] = m2[33]*rx; contrib[36] = m2[33]*ry; contrib[37] = m2[33]*rz;
#pragma unroll
  for (int q = 0; q < 6; ++q) contrib[38 + q] = m2[34 + q];

#pragma unroll
  for (int q = 0; q < 44; ++q) {
    float v = contrib[q];
#pragma unroll
    for (int o = 32; o > 0; o >>= 1) v += __shfl_xor(v, o, 64);
    if (lane == 0) red[wv][q] = v;
  }
  __syncthreads();
  if (t < 44) fin[t] = red[0][t] + red[1][t] + red[2][t] + red[3][t];
  __syncthreads();

  if (t < 16) {  // state_out = [node_i, m_l0] @ Wl0 + bl0
    float a = bl0[t];
#pragma unroll
    for (int k = 0; k < 32; ++k) a = fmaf(ni[k], Wl0[k*16 + t], a);
#pragma unroll
    for (int k = 0; k < 32; ++k) a = fmaf(fin[k] * (1.f/128.f), Wl0[(32+k)*16 + t], a);
    soutf[i*16 + t] = a;
    out[LL*9 + i*16 + t] = a;
  }
  if (t == 0) {  // frame update
    float ve[6], wa[6];
#pragma unroll
    for (int q = 0; q < 6; ++q) ve[q] = fin[32 + q] * (1.f/128.f);
#pragma unroll
    for (int q = 0; q < 6; ++q) wa[q] = fin[38 + q] * (1.f/128.f);
    float l1[9];
#pragma unroll
    for (int a = 0; a < 3; ++a)
#pragma unroll
      for (int d = 0; d < 3; ++d) l1[a*3 + d] = xyz[i*9 + a*3 + d] - xyz[i*9 + 3 + d];
    float T[3], Rv[3];
#pragma unroll
    for (int d = 0; d < 3; ++d) {
      float va0 = wa[0]*l1[d] + wa[1]*l1[3 + d] + wa[2]*l1[6 + d];
      float va1 = wa[3]*l1[d] + wa[4]*l1[3 + d] + wa[5]*l1[6 + d];
      T[d]  = (ve[d] + va0) / 10.f;
      Rv[d] = (ve[3 + d] + va1) / 100.f;
    }
    float qn = sqrtf(1.f + Rv[0]*Rv[0] + Rv[1]*Rv[1] + Rv[2]*Rv[2]);
    float qA = 1.f/qn, qB = Rv[0]/qn, qC = Rv[1]/qn, qD = Rv[2]/qn;
    float Rm[9];
    Rm[0] = qA*qA + qB*qB - qC*qC - qD*qD;
    Rm[1] = 2.f*qB*qC - 2.f*qA*qD;
    Rm[2] = 2.f*qB*qD + 2.f*qA*qC;
    Rm[3] = 2.f*qB*qC + 2.f*qA*qD;
    Rm[4] = qA*qA - qB*qB + qC*qC - qD*qD;
    Rm[5] = 2.f*qC*qD - 2.f*qA*qB;
    Rm[6] = 2.f*qB*qD - 2.f*qA*qC;
    Rm[7] = 2.f*qC*qD + 2.f*qA*qB;
    Rm[8] = qA*qA - qB*qB - qC*qC + qD*qD;
    if (rmask[i]) {
      Rm[0] = 1.f; Rm[1] = 0.f; Rm[2] = 0.f;
      Rm[3] = 0.f; Rm[4] = 1.f; Rm[5] = 0.f;
      Rm[6] = 0.f; Rm[7] = 0.f; Rm[8] = 1.f;
    }
#pragma unroll
    for (int a = 0; a < 3; ++a)
#pragma unroll
      for (int di = 0; di < 3; ++di) {
        float xn = Rm[di*3+0]*l1[a*3+0] + Rm[di*3+1]*l1[a*3+1] + Rm[di*3+2]*l1[a*3+2]
                 + xyz[i*9 + 3 + di] + T[di];
        out[i*9 + a*3 + di] = xn;
      }
  }
}

// ---------------- Kernel D: si MLP stack -> alpha ---------------------------
__global__ __launch_bounds__(128) void kernD(
    const float* __restrict__ seq_ln, const float* __restrict__ st_out,
    const float* __restrict__ Ws0, const float* __restrict__ bs0,
    const float* __restrict__ Wsi, const float* __restrict__ bsi,
    const float* __restrict__ Wp1, const float* __restrict__ bp1,
    const float* __restrict__ Wp2, const float* __restrict__ bp2,
    const float* __restrict__ Wp3, const float* __restrict__ bp3,
    const float* __restrict__ Wp4, const float* __restrict__ bp4,
    const float* __restrict__ Wout, const float* __restrict__ bout,
    float* __restrict__ out)
{
  const int i = blockIdx.x, t = threadIdx.x;
  __shared__ float x0[256], stn[16], ra[128], ga[128], rb[128], gb[128], rc[128];
  x0[t]       = seq_ln[i*256 + t];
  x0[128 + t] = seq_ln[i*256 + 128 + t];
  if (t < 16) {
    float m = 0.f;
    for (int k = 0; k < 16; ++k) m += st_out[i*16 + k];
    m *= (1.f/16.f);
    float v = 0.f;
    for (int k = 0; k < 16; ++k) { float dd = st_out[i*16 + k] - m; v += dd*dd; }
    v *= (1.f/16.f);
    stn[t] = (st_out[i*16 + t] - m) / sqrtf(v + 1e-5f);
  }
  __syncthreads();

  float si = bs0[t] + bsi[t];
  for (int k = 0; k < 256; ++k) si = fmaf(x0[k], Ws0[k*128 + t], si);
  for (int k = 0; k < 16; ++k)  si = fmaf(stn[k], Wsi[k*128 + t], si);
  ra[t] = fmaxf(si, 0.f);
  __syncthreads();
  float h = bp1[t];
  for (int k = 0; k < 128; ++k) h = fmaf(ra[k], Wp1[k*128 + t], h);
  ga[t] = fmaxf(h, 0.f);
  __syncthreads();
  float d2 = bp2[t];
  for (int k = 0; k < 128; ++k) d2 = fmaf(ga[k], Wp2[k*128 + t], d2);
  si += d2;
  rb[t] = fmaxf(si, 0.f);
  __syncthreads();
  float h2 = bp3[t];
  for (int k = 0; k < 128; ++k) h2 = fmaf(rb[k], Wp3[k*128 + t], h2);
  gb[t] = fmaxf(h2, 0.f);
  __syncthreads();
  float d4 = bp4[t];
  for (int k = 0; k < 128; ++k) d4 = fmaf(gb[k], Wp4[k*128 + t], d4);
  si += d4;
  rc[t] = fmaxf(si, 0.f);
  __syncthreads();
  if (t < 20) {
    float a = bout[t];
    for (int k = 0; k < 128; ++k) a = fmaf(rc[k], Wout[k*20 + t], a);
    out[19200 + i*20 + t] = a;
  }
}

extern "C" void kernel_launch(void* const* d_in, const int* in_sizes, int n_in,
                              void* d_out, int out_size, void* d_ws, size_t ws_size,
                              hipStream_t stream)
{
  (void)in_sizes; (void)n_in; (void)out_size; (void)ws_size;
  const float* msa   = (const float*)d_in[0];
  const float* pair  = (const float*)d_in[1];
  const float* xyz   = (const float*)d_in[2];
  const float* state = (const float*)d_in[3];
  const int*   idx   = (const int*)d_in[4];
  const unsigned char* rmask = (const unsigned char*)d_in[5];
  const float* W_en = (const float*)d_in[6];
  const float* b_en = (const float*)d_in[7];
  const float* Wn1  = (const float*)d_in[8];
  const float* bn1  = (const float*)d_in[9];
  const float* Wn2  = (const float*)d_in[10];
  const float* bn2  = (const float*)d_in[11];
  const float* W_ee = (const float*)d_in[12];
  const float* b_ee = (const float*)d_in[13];
  const float* We1  = (const float*)d_in[14];
  const float* be1  = (const float*)d_in[15];
  const float* We2  = (const float*)d_in[16];
  const float* be2  = (const float*)d_in[17];
  const float* Wm1  = (const float*)d_in[18];
  const float* bm1  = (const float*)d_in[19];
  const float* Wm2  = (const float*)d_in[20];
  const float* bm2  = (const float*)d_in[21];
  const float* Wl0  = (const float*)d_in[22];
  const float* bl0  = (const float*)d_in[23];
  const float* Ws0  = (const float*)d_in[24];
  const float* bs0  = (const float*)d_in[25];
  const float* Wsi  = (const float*)d_in[26];
  const float* bsi  = (const float*)d_in[27];
  const float* Wp1  = (const float*)d_in[28];
  const float* bp1  = (const float*)d_in[29];
  const float* Wp2  = (const float*)d_in[30];
  const float* bp2  = (const float*)d_in[31];
  const float* Wp3  = (const float*)d_in[32];
  const float* bp3  = (const float*)d_in[33];
  const float* Wp4  = (const float*)d_in[34];
  const float* bp4  = (const float*)d_in[35];
  const float* Wout = (const float*)d_in[36];
  const float* bout = (const float*)d_in[37];

  float* wsf    = (float*)d_ws;
  float* seq_ln = wsf + WS_SEQ;
  float* nodev  = wsf + WS_NODE;
  int*   nbr    = (int*)(wsf + WS_NBR);
  float* soutf  = wsf + WS_SOUT;
  float* colsum = wsf + WS_COL;
  float* out = (float*)d_out;

  kernP<<<1, 32, 0, stream>>>(W_ee, colsum);
  kernA<<<LL, 256, 0, stream>>>(msa, state, W_en, b_en, Wn1, bn1, Wn2, bn2, seq_ln, nodev);
  kernB<<<LL, 256, 0, stream>>>(xyz, nbr);
  kernC<<<LL, 256, 0, stream>>>(pair, xyz, idx, rmask, W_ee, b_ee, We1, be1, We2, be2,
                                Wm1, bm1, Wm2, bm2, Wl0, bl0, nodev, nbr, colsum, soutf, out);
  kernD<<<LL, 128, 0, stream>>>(seq_ln, soutf, Ws0, bs0, Wsi, bsi, Wp1, bp1, Wp2, bp2,
                                Wp3, bp3, Wp4, bp4, Wout, bout, out);
}

// Round 4
// 306.600 us; speedup vs baseline: 5.5959x; 5.5959x over previous
//
#include <hip/hip_runtime.h>
#include <hip/hip_bf16.h>

#define LL 768
#define TOPK 128

// workspace layout (floats)
#define WS_SEQ  0                        // 768*256 = 196608
#define WS_NODE (WS_SEQ + LL*256)        // 768*32  = 24576
#define WS_NBR  (WS_NODE + LL*32)        // 768*128 ints
#define WS_SOUT (WS_NBR + LL*TOPK)       // 768*16
#define WS_CSEE (WS_SOUT + LL*16)        // 32
#define WS_CSE1 (WS_CSEE + 32)           // 64
#define WS_E0   (WS_CSE1 + 64)           // 768*128*32 floats (16B-aligned)

#define FMA_ROW32(ACC, XVAL, WPTR) do {                                   \
    const float _x = (XVAL);                                              \
    const float* __restrict__ _w = (WPTR);                                \
    _Pragma("unroll")                                                     \
    for (int _c = 0; _c < 32; ++_c) ACC[_c] = fmaf(_x, _w[_c], ACC[_c]);  \
  } while (0)

__device__ __forceinline__ float block_sum_256(float v, float* red, int t) {
#pragma unroll
  for (int o = 32; o > 0; o >>= 1) v += __shfl_xor(v, o, 64);
  __syncthreads();
  if ((t & 63) == 0) red[t >> 6] = v;
  __syncthreads();
  return red[0] + red[1] + red[2] + red[3];
}

// ---------------- Kernel P: column sums (LN-linearity hoists) --------------
__global__ void kernP(const float* __restrict__ W_ee, const float* __restrict__ We1,
                      float* __restrict__ colsum_ee, float* __restrict__ colsum_e1)
{
  const int c = threadIdx.x;   // 64 threads
  if (c < 32) {
    float s = 0.f;
    for (int k = 0; k < 128; ++k) s += W_ee[k*32 + c];
    colsum_ee[c] = s;
  }
  float s2 = 0.f;
  for (int k = 0; k < 32; ++k) s2 += We1[k*64 + c];
  colsum_e1[c] = s2;
}

// ---------------- Kernel A: seq LN, state LN, node MLP + LN ----------------
__global__ __launch_bounds__(256) void kernA(
    const float* __restrict__ msa, const float* __restrict__ state,
    const float* __restrict__ W_en, const float* __restrict__ b_en,
    const float* __restrict__ Wn1, const float* __restrict__ bn1,
    const float* __restrict__ Wn2, const float* __restrict__ bn2,
    float* __restrict__ seq_ln, float* __restrict__ nodeo)
{
  const int i = blockIdx.x, t = threadIdx.x;
  __shared__ float x[256];
  __shared__ float red[4];
  __shared__ float sn[16], n0[32], tn[32], hh[64], n1v[32];

  float v = msa[i*256 + t];
  float mean = block_sum_256(v, red, t) * (1.f/256.f);
  float d = v - mean;
  float var = block_sum_256(d*d, red, t) * (1.f/256.f);
  float xn = d / sqrtf(var + 1e-5f);
  x[t] = xn;
  seq_ln[i*256 + t] = xn;

  if (t < 16) {
    float m2 = 0.f;
    for (int k = 0; k < 16; ++k) m2 += state[i*16 + k];
    m2 *= (1.f/16.f);
    float v2 = 0.f;
    for (int k = 0; k < 16; ++k) { float dd = state[i*16 + k] - m2; v2 += dd*dd; }
    v2 *= (1.f/16.f);
    sn[t] = (state[i*16 + t] - m2) / sqrtf(v2 + 1e-5f);
  }
  __syncthreads();

  if (t < 32) {
    float a = b_en[t];
    for (int k = 0; k < 256; ++k) a = fmaf(x[k], W_en[k*32 + t], a);
    for (int k = 0; k < 16; ++k)  a = fmaf(sn[k], W_en[(256+k)*32 + t], a);
    n0[t] = a;
  }
  __syncthreads();
  if (t < 32) {
    float m = 0.f;
    for (int k = 0; k < 32; ++k) m += n0[k];
    m *= (1.f/32.f);
    float vv = 0.f;
    for (int k = 0; k < 32; ++k) { float dd = n0[k] - m; vv += dd*dd; }
    vv *= (1.f/32.f);
    tn[t] = (n0[t] - m) / sqrtf(vv + 1e-5f);
  }
  __syncthreads();
  if (t < 64) {
    float a = bn1[t];
    for (int k = 0; k < 32; ++k) a = fmaf(tn[k], Wn1[k*64 + t], a);
    hh[t] = fmaxf(a, 0.f);
  }
  __syncthreads();
  if (t < 32) {
    float a = n0[t] + bn2[t];
    for (int k = 0; k < 64; ++k) a = fmaf(hh[k], Wn2[k*32 + t], a);
    n1v[t] = a;
  }
  __syncthreads();
  if (t < 32) {
    float m = 0.f;
    for (int k = 0; k < 32; ++k) m += n1v[k];
    m *= (1.f/32.f);
    float vv = 0.f;
    for (int k = 0; k < 32; ++k) { float dd = n1v[k] - m; vv += dd*dd; }
    vv *= (1.f/32.f);
    nodeo[i*32 + t] = (n1v[t] - m) / sqrtf(vv + 1e-5f);
  }
}

// ---------------- Kernel B: top-128 nearest by D, bitonic (D_bits, j) -------
__global__ __launch_bounds__(256) void kernB(const float* __restrict__ xyz,
                                             int* __restrict__ nbr)
{
  const int i = blockIdx.x, t = threadIdx.x;
  __shared__ unsigned long long keys[1024];
  const float cix = xyz[i*9+3], ciy = xyz[i*9+4], ciz = xyz[i*9+5];

  for (int j = t; j < 1024; j += 256) {
    unsigned long long kk = ~0ull;
    if (j < LL) {
      float dx = __fadd_rn(cix, -xyz[j*9+3]);
      float dy = __fadd_rn(ciy, -xyz[j*9+4]);
      float dz = __fadd_rn(ciz, -xyz[j*9+5]);
      float Dv = sqrtf(__fadd_rn(__fadd_rn(__fadd_rn(__fmul_rn(dx,dx),
                         __fmul_rn(dy,dy)), __fmul_rn(dz,dz)), 1e-8f));
      kk = (((unsigned long long)__float_as_uint(Dv)) << 32) | (unsigned)j;
    }
    keys[j] = kk;
  }
  for (int size = 2; size <= 1024; size <<= 1) {
    for (int stride = size >> 1; stride > 0; stride >>= 1) {
      __syncthreads();
      for (int p = t; p < 512; p += 256) {
        int lo = 2*p - (p & (stride - 1));
        int hi = lo + stride;
        bool up = ((lo & size) == 0);
        unsigned long long a = keys[lo], b = keys[hi];
        if ((a > b) == up) { keys[lo] = b; keys[hi] = a; }
      }
    }
  }
  __syncthreads();
  if (t < TOPK) nbr[i*TOPK + t] = (int)(keys[t] & 0xffffffffu);
}

// ---------------- Kernel C1: edge0 (pre-LN) per selected edge --------------
// 4 lanes per edge: lane = q*16 + slot; k-split 4-way over pair row & RBF.
// blockIdx.x = i*2 + part; wave wv handles edges [part*64 + wv*16, +16).
__global__ __launch_bounds__(256) void kernC1(
    const float* __restrict__ pair, const float* __restrict__ xyz,
    const int* __restrict__ idx,
    const float* __restrict__ W_ee, const float* __restrict__ b_ee,
    const float* __restrict__ colsum_ee,
    const int* __restrict__ nbr, float* __restrict__ e0ws)
{
  const int i = blockIdx.x >> 1, part = blockIdx.x & 1;
  const int t = threadIdx.x, lane = t & 63, wv = t >> 6;
  const int slot = lane & 15, q = lane >> 4;     // q = 0..3 k-quarter
  const int p = part*64 + wv*16 + slot;          // neighbor slot 0..127

  const int j = nbr[i*TOPK + p];
  const float cix = xyz[i*9+3], ciy = xyz[i*9+4], ciz = xyz[i*9+5];
  const float dx = __fadd_rn(cix, -xyz[j*9+3]);
  const float dy = __fadd_rn(ciy, -xyz[j*9+4]);
  const float dz = __fadd_rn(ciz, -xyz[j*9+5]);
  const float Dv = sqrtf(__fadd_rn(__fadd_rn(__fadd_rn(__fmul_rn(dx,dx),
                      __fmul_rn(dy,dy)), __fmul_rn(dz,dz)), 1e-8f));

  // this lane's 32 floats of the pair row
  const float* prow = pair + (((size_t)i*LL + j) * 128) + q*32;
  float acc[32];
#pragma unroll
  for (int c = 0; c < 32; ++c) acc[c] = 0.f;
  float s = 0.f, ss = 0.f;
#pragma unroll 2
  for (int q4 = 0; q4 < 8; ++q4) {
    float4 v = ((const float4*)prow)[q4];
    s  += (v.x + v.y) + (v.z + v.w);
    ss += v.x*v.x + v.y*v.y + v.z*v.z + v.w*v.w;
    const float* wr = W_ee + (q*32 + q4*4)*32;
    FMA_ROW32(acc, v.x, wr);
    FMA_ROW32(acc, v.y, wr + 32);
    FMA_ROW32(acc, v.z, wr + 64);
    FMA_ROW32(acc, v.w, wr + 96);
  }
  s  += __shfl_xor(s, 16);  s  += __shfl_xor(s, 32);
  ss += __shfl_xor(ss, 16); ss += __shfl_xor(ss, 32);
  const float pm  = s * (1.f/128.f);
  const float pvv = ss * (1.f/128.f) - pm*pm;
  const float prs = 1.f / sqrtf(pvv + 1e-5f);

#pragma unroll
  for (int c = 0; c < 32; ++c) acc[c] *= prs;

  // RBF part: this lane's 16 of 64 kernels
#pragma unroll 4
  for (int kk = 0; kk < 16; ++kk) {
    const int k = q*16 + kk;
    float mu = 2.f + (float)k * (20.f/63.f);
    float u  = (Dv - mu) / 0.3125f;
    FMA_ROW32(acc, expf(-(u*u)), W_ee + (128+k)*32);
  }
  if (q == 0) {   // seqsep + bias + LN affine correction (counted once)
    const float offv = (float)(idx[j] - idx[i]);
    const float sg = (offv > 0.f) ? 1.f : ((offv < 0.f) ? -1.f : 0.f);
    const float xsep = sg * logf(fabsf(offv) + 1.f);
    FMA_ROW32(acc, xsep, W_ee + 192*32);
    const float corr = -prs * pm;
#pragma unroll
    for (int c = 0; c < 32; ++c) acc[c] += b_ee[c] + corr * colsum_ee[c];
  }
#pragma unroll
  for (int c = 0; c < 32; ++c) {
    acc[c] += __shfl_xor(acc[c], 16);
    acc[c] += __shfl_xor(acc[c], 32);
  }

  // store full e0: lane q writes channel-quads 2q, 2q+1; layout [i][c4][p]
  float4* e4 = (float4*)e0ws;
#pragma unroll
  for (int cc = 0; cc < 2; ++cc) {
    const int c4 = q*2 + cc;
    float4 w = make_float4(acc[c4*4], acc[c4*4+1], acc[c4*4+2], acc[c4*4+3]);
    e4[((size_t)i*8 + c4)*128 + p] = w;
  }
}

// ---------------- Kernel C2: edge MLP + message MLP + reduce ---------------
// 2 lanes per edge (half = lane>>5), output-split channels.
__global__ __launch_bounds__(256) void kernC2(
    const float* __restrict__ xyz, const unsigned char* __restrict__ rmask,
    const float* __restrict__ We1, const float* __restrict__ be1,
    const float* __restrict__ We2, const float* __restrict__ be2,
    const float* __restrict__ Wm1, const float* __restrict__ bm1,
    const float* __restrict__ Wm2, const float* __restrict__ bm2,
    const float* __restrict__ Wl0, const float* __restrict__ bl0,
    const float* __restrict__ node, const int* __restrict__ nbr,
    const float* __restrict__ colsum_e1, const float* __restrict__ e0ws,
    float* __restrict__ soutf, float* __restrict__ out)
{
  const int i = blockIdx.x, t = threadIdx.x;
  const int lane = t & 63, wv = t >> 6;
  const int p = wv*32 + (lane & 31);
  const int half = lane >> 5;
  __shared__ float ni[32];
  __shared__ float nd[128*33];   // padded: bank-conflict-free reads
  __shared__ float red[4][44];
  __shared__ float fin[44];

  if (t < 32) ni[t] = node[i*32 + t];
  {  // stage neighbor node rows: thread t loads 16 floats of row pp
    const int pp = t >> 1, hh = t & 1;
    const int jj = nbr[i*TOPK + pp];
    const float* nr = node + jj*32 + hh*16;
    float4 a0 = ((const float4*)nr)[0];
    float4 a1 = ((const float4*)nr)[1];
    float4 a2 = ((const float4*)nr)[2];
    float4 a3 = ((const float4*)nr)[3];
    float* dst = nd + pp*33 + hh*16;
    dst[0]=a0.x; dst[1]=a0.y; dst[2]=a0.z; dst[3]=a0.w;
    dst[4]=a1.x; dst[5]=a1.y; dst[6]=a1.z; dst[7]=a1.w;
    dst[8]=a2.x; dst[9]=a2.y; dst[10]=a2.z; dst[11]=a2.w;
    dst[12]=a3.x; dst[13]=a3.y; dst[14]=a3.z; dst[15]=a3.w;
  }
  __syncthreads();

  // load full e0 (both halves read the same — L1 broadcast)
  float e0[32];
#pragma unroll
  for (int c4 = 0; c4 < 8; ++c4) {
    float4 v = ((const float4*)e0ws)[((size_t)i*8 + c4)*128 + p];
    e0[c4*4+0]=v.x; e0[c4*4+1]=v.y; e0[c4*4+2]=v.z; e0[c4*4+3]=v.w;
  }
  // LN(e0) stats (lane-local; both halves identical)
  float m = 0.f;
#pragma unroll
  for (int c = 0; c < 32; ++c) m += e0[c];
  m *= (1.f/32.f);
  float vv = 0.f;
#pragma unroll
  for (int c = 0; c < 32; ++c) { float dd = e0[c]-m; vv += dd*dd; }
  vv *= (1.f/32.f);
  const float rs = 1.f / sqrtf(vv + 1e-5f);

  // h = relu( rs*(e0@We1) - rs*m*colsum_e1 + be1 ), output-split (32 ch/lane)
  float h[32];
#pragma unroll
  for (int c = 0; c < 32; ++c) h[c] = 0.f;
#pragma unroll 8
  for (int k = 0; k < 32; ++k) {
    const float xv = e0[k];
    const float* wr = We1 + k*64 + half*32;
#pragma unroll
    for (int c = 0; c < 32; ++c) h[c] = fmaf(xv, wr[c], h[c]);
  }
  {
    const float mr = m * rs;
    const float* cs = colsum_e1 + half*32;
    const float* b1 = be1 + half*32;
#pragma unroll
    for (int c = 0; c < 32; ++c)
      h[c] = fmaxf(fmaf(rs, h[c], fmaf(-mr, cs[c], b1[c])), 0.f);
  }

  // f(=e2 partial) built in place over e0: half0 keeps residual+bias
#pragma unroll
  for (int c = 0; c < 32; ++c) e0[c] = half ? 0.f : (e0[c] + be2[c]);
#pragma unroll 8
  for (int k = 0; k < 32; ++k) {
    const float xv = h[k];
    const float* wr = We2 + (half*32 + k)*32;
#pragma unroll
    for (int c = 0; c < 32; ++c) e0[c] = fmaf(xv, wr[c], e0[c]);
  }
#pragma unroll
  for (int c = 0; c < 32; ++c) e0[c] += __shfl_xor(e0[c], 32);  // full e2

  // ed2 = LN(e2) in place (e2 dead after m1)
  float mf = 0.f;
#pragma unroll
  for (int c = 0; c < 32; ++c) mf += e0[c];
  mf *= (1.f/32.f);
  float vf = 0.f;
#pragma unroll
  for (int c = 0; c < 32; ++c) { float dd = e0[c]-mf; vf += dd*dd; }
  vf *= (1.f/32.f);
  const float rsf = 1.f / sqrtf(vf + 1e-5f);
#pragma unroll
  for (int c = 0; c < 32; ++c) e0[c] = (e0[c] - mf) * rsf;

  // m1 = relu([ni, nj, ed2] @ Wm1 + bm1), output-split
  float m1[32];
  {
    const float* bb = bm1 + half*32;
#pragma unroll
    for (int c = 0; c < 32; ++c) m1[c] = bb[c];
  }
#pragma unroll 8
  for (int k = 0; k < 32; ++k) {
    const float xv = ni[k];
    const float* wr = Wm1 + k*64 + half*32;
#pragma unroll
    for (int c = 0; c < 32; ++c) m1[c] = fmaf(xv, wr[c], m1[c]);
  }
  {
    const float* nrow = nd + p*33;
#pragma unroll 8
    for (int k = 0; k < 32; ++k) {
      const float xv = nrow[k];
      const float* wr = Wm1 + (32+k)*64 + half*32;
#pragma unroll
      for (int c = 0; c < 32; ++c) m1[c] = fmaf(xv, wr[c], m1[c]);
    }
  }
#pragma unroll 8
  for (int k = 0; k < 32; ++k) {
    const float xv = e0[k];
    const float* wr = Wm1 + (64+k)*64 + half*32;
#pragma unroll
    for (int c = 0; c < 32; ++c) m1[c] = fmaf(xv, wr[c], m1[c]);
  }
#pragma unroll
  for (int c = 0; c < 32; ++c) m1[c] = fmaxf(m1[c], 0.f);

  // m2 = m1 @ Wm2 + bm2 (k-partial per half; downstream is linear+summed)
  float m2[40];
#pragma unroll
  for (int o = 0; o < 40; ++o) m2[o] = half ? 0.f : bm2[o];
#pragma unroll 8
  for (int k = 0; k < 32; ++k) {
    const float xv = m1[k];
    const float* wr = Wm2 + (half*32 + k)*40;
#pragma unroll
    for (int o = 0; o < 40; ++o) m2[o] = fmaf(xv, wr[o], m2[o]);
  }

  // contributions -> block reduce
  const int j = nbr[i*TOPK + p];
  const float rx = xyz[j*9+3] - xyz[i*9+3];
  const float ry = xyz[j*9+4] - xyz[i*9+4];
  const float rz = xyz[j*9+5] - xyz[i*9+5];
  float contrib[44];
#pragma unroll
  for (int qq = 0; qq < 32; ++qq) contrib[qq] = m2[qq];
  contrib[32] = m2[32]*rx; contrib[33] = m2[32]*ry; contrib[34] = m2[32]*rz;
  contrib[35] = m2[33]*rx; contrib[36] = m2[33]*ry; contrib[37] = m2[33]*rz;
#pragma unroll
  for (int qq = 0; qq < 6; ++qq) contrib[38 + qq] = m2[34 + qq];

#pragma unroll
  for (int qq = 0; qq < 44; ++qq) {
    float v = contrib[qq];
#pragma unroll
    for (int o = 32; o > 0; o >>= 1) v += __shfl_xor(v, o, 64);
    if (lane == 0) red[wv][qq] = v;
  }
  __syncthreads();
  if (t < 44) fin[t] = red[0][t] + red[1][t] + red[2][t] + red[3][t];
  __syncthreads();

  if (t < 16) {  // state_out = [node_i, m_l0] @ Wl0 + bl0
    float a = bl0[t];
#pragma unroll
    for (int k = 0; k < 32; ++k) a = fmaf(ni[k], Wl0[k*16 + t], a);
#pragma unroll
    for (int k = 0; k < 32; ++k) a = fmaf(fin[k] * (1.f/128.f), Wl0[(32+k)*16 + t], a);
    soutf[i*16 + t] = a;
    out[LL*9 + i*16 + t] = a;
  }
  if (t == 0) {  // frame update
    float ve[6], wa[6];
#pragma unroll
    for (int qq = 0; qq < 6; ++qq) ve[qq] = fin[32 + qq] * (1.f/128.f);
#pragma unroll
    for (int qq = 0; qq < 6; ++qq) wa[qq] = fin[38 + qq] * (1.f/128.f);
    float l1[9];
#pragma unroll
    for (int a = 0; a < 3; ++a)
#pragma unroll
      for (int d = 0; d < 3; ++d) l1[a*3 + d] = xyz[i*9 + a*3 + d] - xyz[i*9 + 3 + d];
    float T[3], Rv[3];
#pragma unroll
    for (int d = 0; d < 3; ++d) {
      float va0 = wa[0]*l1[d] + wa[1]*l1[3 + d] + wa[2]*l1[6 + d];
      float va1 = wa[3]*l1[d] + wa[4]*l1[3 + d] + wa[5]*l1[6 + d];
      T[d]  = (ve[d] + va0) / 10.f;
      Rv[d] = (ve[3 + d] + va1) / 100.f;
    }
    float qn = sqrtf(1.f + Rv[0]*Rv[0] + Rv[1]*Rv[1] + Rv[2]*Rv[2]);
    float qA = 1.f/qn, qB = Rv[0]/qn, qC = Rv[1]/qn, qD = Rv[2]/qn;
    float Rm[9];
    Rm[0] = qA*qA + qB*qB - qC*qC - qD*qD;
    Rm[1] = 2.f*qB*qC - 2.f*qA*qD;
    Rm[2] = 2.f*qB*qD + 2.f*qA*qC;
    Rm[3] = 2.f*qB*qC + 2.f*qA*qD;
    Rm[4] = qA*qA - qB*qB + qC*qC - qD*qD;
    Rm[5] = 2.f*qC*qD - 2.f*qA*qB;
    Rm[6] = 2.f*qB*qD - 2.f*qA*qC;
    Rm[7] = 2.f*qC*qD + 2.f*qA*qB;
    Rm[8] = qA*qA - qB*qB - qC*qC + qD*qD;
    if (rmask[i]) {
      Rm[0] = 1.f; Rm[1] = 0.f; Rm[2] = 0.f;
      Rm[3] = 0.f; Rm[4] = 1.f; Rm[5] = 0.f;
      Rm[6] = 0.f; Rm[7] = 0.f; Rm[8] = 1.f;
    }
#pragma unroll
    for (int a = 0; a < 3; ++a)
#pragma unroll
      for (int di = 0; di < 3; ++di) {
        float xn = Rm[di*3+0]*l1[a*3+0] + Rm[di*3+1]*l1[a*3+1] + Rm[di*3+2]*l1[a*3+2]
                 + xyz[i*9 + 3 + di] + T[di];
        out[i*9 + a*3 + di] = xn;
      }
  }
}

// ---------------- Kernel D: si MLP stack -> alpha ---------------------------
__global__ __launch_bounds__(128) void kernD(
    const float* __restrict__ seq_ln, const float* __restrict__ st_out,
    const float* __restrict__ Ws0, const float* __restrict__ bs0,
    const float* __restrict__ Wsi, const float* __restrict__ bsi,
    const float* __restrict__ Wp1, const float* __restrict__ bp1,
    const float* __restrict__ Wp2, const float* __restrict__ bp2,
    const float* __restrict__ Wp3, const float* __restrict__ bp3,
    const float* __restrict__ Wp4, const float* __restrict__ bp4,
    const float* __restrict__ Wout, const float* __restrict__ bout,
    float* __restrict__ out)
{
  const int i = blockIdx.x, t = threadIdx.x;
  __shared__ float x0[256], stn[16], ra[128], ga[128], rb[128], gb[128], rc[128];
  x0[t]       = seq_ln[i*256 + t];
  x0[128 + t] = seq_ln[i*256 + 128 + t];
  if (t < 16) {
    float m = 0.f;
    for (int k = 0; k < 16; ++k) m += st_out[i*16 + k];
    m *= (1.f/16.f);
    float v = 0.f;
    for (int k = 0; k < 16; ++k) { float dd = st_out[i*16 + k] - m; v += dd*dd; }
    v *= (1.f/16.f);
    stn[t] = (st_out[i*16 + t] - m) / sqrtf(v + 1e-5f);
  }
  __syncthreads();

  float si = bs0[t] + bsi[t];
  for (int k = 0; k < 256; ++k) si = fmaf(x0[k], Ws0[k*128 + t], si);
  for (int k = 0; k < 16; ++k)  si = fmaf(stn[k], Wsi[k*128 + t], si);
  ra[t] = fmaxf(si, 0.f);
  __syncthreads();
  float h = bp1[t];
  for (int k = 0; k < 128; ++k) h = fmaf(ra[k], Wp1[k*128 + t], h);
  ga[t] = fmaxf(h, 0.f);
  __syncthreads();
  float d2 = bp2[t];
  for (int k = 0; k < 128; ++k) d2 = fmaf(ga[k], Wp2[k*128 + t], d2);
  si += d2;
  rb[t] = fmaxf(si, 0.f);
  __syncthreads();
  float h2 = bp3[t];
  for (int k = 0; k < 128; ++k) h2 = fmaf(rb[k], Wp3[k*128 + t], h2);
  gb[t] = fmaxf(h2, 0.f);
  __syncthreads();
  float d4 = bp4[t];
  for (int k = 0; k < 128; ++k) d4 = fmaf(gb[k], Wp4[k*128 + t], d4);
  si += d4;
  rc[t] = fmaxf(si, 0.f);
  __syncthreads();
  if (t < 20) {
    float a = bout[t];
    for (int k = 0; k < 128; ++k) a = fmaf(rc[k], Wout[k*20 + t], a);
    out[19200 + i*20 + t] = a;
  }
}

extern "C" void kernel_launch(void* const* d_in, const int* in_sizes, int n_in,
                              void* d_out, int out_size, void* d_ws, size_t ws_size,
                              hipStream_t stream)
{
  (void)in_sizes; (void)n_in; (void)out_size; (void)ws_size;
  const float* msa   = (const float*)d_in[0];
  const float* pair  = (const float*)d_in[1];
  const float* xyz   = (const float*)d_in[2];
  const float* state = (const float*)d_in[3];
  const int*   idx   = (const int*)d_in[4];
  const unsigned char* rmask = (const unsigned char*)d_in[5];
  const float* W_en = (const float*)d_in[6];
  const float* b_en = (const float*)d_in[7];
  const float* Wn1  = (const float*)d_in[8];
  const float* bn1  = (const float*)d_in[9];
  const float* Wn2  = (const float*)d_in[10];
  const float* bn2  = (const float*)d_in[11];
  const float* W_ee = (const float*)d_in[12];
  const float* b_ee = (const float*)d_in[13];
  const float* We1  = (const float*)d_in[14];
  const float* be1  = (const float*)d_in[15];
  const float* We2  = (const float*)d_in[16];
  const float* be2  = (const float*)d_in[17];
  const float* Wm1  = (const float*)d_in[18];
  const float* bm1  = (const float*)d_in[19];
  const float* Wm2  = (const float*)d_in[20];
  const float* bm2  = (const float*)d_in[21];
  const float* Wl0  = (const float*)d_in[22];
  const float* bl0  = (const float*)d_in[23];
  const float* Ws0  = (const float*)d_in[24];
  const float* bs0  = (const float*)d_in[25];
  const float* Wsi  = (const float*)d_in[26];
  const float* bsi  = (const float*)d_in[27];
  const float* Wp1  = (const float*)d_in[28];
  const float* bp1  = (const float*)d_in[29];
  const float* Wp2  = (const float*)d_in[30];
  const float* bp2  = (const float*)d_in[31];
  const float* Wp3  = (const float*)d_in[32];
  const float* bp3  = (const float*)d_in[33];
  const float* Wp4  = (const float*)d_in[34];
  const float* bp4  = (const float*)d_in[35];
  const float* Wout = (const float*)d_in[36];
  const float* bout = (const float*)d_in[37];

  float* wsf    = (float*)d_ws;
  float* seq_ln = wsf + WS_SEQ;
  float* nodev  = wsf + WS_NODE;
  int*   nbr    = (int*)(wsf + WS_NBR);
  float* soutf  = wsf + WS_SOUT;
  float* csee   = wsf + WS_CSEE;
  float* cse1   = wsf + WS_CSE1;
  float* e0ws   = wsf + WS_E0;
  float* out = (float*)d_out;

  kernP<<<1, 64, 0, stream>>>(W_ee, We1, csee, cse1);
  kernA<<<LL, 256, 0, stream>>>(msa, state, W_en, b_en, Wn1, bn1, Wn2, bn2, seq_ln, nodev);
  kernB<<<LL, 256, 0, stream>>>(xyz, nbr);
  kernC1<<<LL*2, 256, 0, stream>>>(pair, xyz, idx, W_ee, b_ee, csee, nbr, e0ws);
  kernC2<<<LL, 256, 0, stream>>>(xyz, rmask, We1, be1, We2, be2, Wm1, bm1, Wm2, bm2,
                                 Wl0, bl0, nodev, nbr, cse1, e0ws, soutf, out);
  kernD<<<LL, 128, 0, stream>>>(seq_ln, soutf, Ws0, bs0, Wsi, bsi, Wp1, bp1, Wp2, bp2,
                                Wp3, bp3, Wp4, bp4, Wout, bout, out);
}

// Round 5
// 197.098 us; speedup vs baseline: 8.7049x; 1.5556x over previous
//
#include <hip/hip_runtime.h>
#include <hip/hip_bf16.h>

#define LL 768
#define TOPK 128

// workspace layout (floats)
#define WS_SEQ  0                        // 768*256
#define WS_NODE (WS_SEQ + LL*256)        // 768*32
#define WS_NBR  (WS_NODE + LL*32)        // 768*128 ints
#define WS_SOUT (WS_NBR + LL*TOPK)       // 768*16
#define WS_CSEE (WS_SOUT + LL*16)        // 32
#define WS_CSE1 (WS_CSEE + 32)           // 64
#define WS_E0   (WS_CSE1 + 64)           // 768*128*32 floats

#define FMA_ROW32(ACC, XVAL, WPTR) do {                                   \
    const float _x = (XVAL);                                              \
    const float* __restrict__ _w = (WPTR);                                \
    _Pragma("unroll")                                                     \
    for (int _c = 0; _c < 32; ++_c) ACC[_c] = fmaf(_x, _w[_c], ACC[_c]);  \
  } while (0)

__device__ __forceinline__ float block_sum_256(float v, float* red, int t) {
#pragma unroll
  for (int o = 32; o > 0; o >>= 1) v += __shfl_xor(v, o, 64);
  __syncthreads();
  if ((t & 63) == 0) red[t >> 6] = v;
  __syncthreads();
  return red[0] + red[1] + red[2] + red[3];
}

// ---------------- Kernel P: column sums (LN-linearity hoist for C1) --------
__global__ void kernP(const float* __restrict__ W_ee, float* __restrict__ colsum_ee)
{
  const int c = threadIdx.x;   // 32 threads
  float s = 0.f;
  for (int k = 0; k < 128; ++k) s += W_ee[k*32 + c];
  colsum_ee[c] = s;
}

// ---------------- Kernel A: seq LN, state LN, node MLP + LN ----------------
__global__ __launch_bounds__(256) void kernA(
    const float* __restrict__ msa, const float* __restrict__ state,
    const float* __restrict__ W_en, const float* __restrict__ b_en,
    const float* __restrict__ Wn1, const float* __restrict__ bn1,
    const float* __restrict__ Wn2, const float* __restrict__ bn2,
    float* __restrict__ seq_ln, float* __restrict__ nodeo)
{
  const int i = blockIdx.x, t = threadIdx.x;
  __shared__ float x[256];
  __shared__ float red[4];
  __shared__ float sn[16], n0[32], tn[32], hh[64], n1v[32];

  float v = msa[i*256 + t];
  float mean = block_sum_256(v, red, t) * (1.f/256.f);
  float d = v - mean;
  float var = block_sum_256(d*d, red, t) * (1.f/256.f);
  float xn = d / sqrtf(var + 1e-5f);
  x[t] = xn;
  seq_ln[i*256 + t] = xn;

  if (t < 16) {
    float m2 = 0.f;
    for (int k = 0; k < 16; ++k) m2 += state[i*16 + k];
    m2 *= (1.f/16.f);
    float v2 = 0.f;
    for (int k = 0; k < 16; ++k) { float dd = state[i*16 + k] - m2; v2 += dd*dd; }
    v2 *= (1.f/16.f);
    sn[t] = (state[i*16 + t] - m2) / sqrtf(v2 + 1e-5f);
  }
  __syncthreads();

  if (t < 32) {
    float a = b_en[t];
    for (int k = 0; k < 256; ++k) a = fmaf(x[k], W_en[k*32 + t], a);
    for (int k = 0; k < 16; ++k)  a = fmaf(sn[k], W_en[(256+k)*32 + t], a);
    n0[t] = a;
  }
  __syncthreads();
  if (t < 32) {
    float m = 0.f;
    for (int k = 0; k < 32; ++k) m += n0[k];
    m *= (1.f/32.f);
    float vv = 0.f;
    for (int k = 0; k < 32; ++k) { float dd = n0[k] - m; vv += dd*dd; }
    vv *= (1.f/32.f);
    tn[t] = (n0[t] - m) / sqrtf(vv + 1e-5f);
  }
  __syncthreads();
  if (t < 64) {
    float a = bn1[t];
    for (int k = 0; k < 32; ++k) a = fmaf(tn[k], Wn1[k*64 + t], a);
    hh[t] = fmaxf(a, 0.f);
  }
  __syncthreads();
  if (t < 32) {
    float a = n0[t] + bn2[t];
    for (int k = 0; k < 64; ++k) a = fmaf(hh[k], Wn2[k*32 + t], a);
    n1v[t] = a;
  }
  __syncthreads();
  if (t < 32) {
    float m = 0.f;
    for (int k = 0; k < 32; ++k) m += n1v[k];
    m *= (1.f/32.f);
    float vv = 0.f;
    for (int k = 0; k < 32; ++k) { float dd = n1v[k] - m; vv += dd*dd; }
    vv *= (1.f/32.f);
    nodeo[i*32 + t] = (n1v[t] - m) / sqrtf(vv + 1e-5f);
  }
}

// ---------------- Kernel B: top-128 nearest by D, bitonic (D_bits, j) -------
__global__ __launch_bounds__(256) void kernB(const float* __restrict__ xyz,
                                             int* __restrict__ nbr)
{
  const int i = blockIdx.x, t = threadIdx.x;
  __shared__ unsigned long long keys[1024];
  const float cix = xyz[i*9+3], ciy = xyz[i*9+4], ciz = xyz[i*9+5];

  for (int j = t; j < 1024; j += 256) {
    unsigned long long kk = ~0ull;
    if (j < LL) {
      float dx = __fadd_rn(cix, -xyz[j*9+3]);
      float dy = __fadd_rn(ciy, -xyz[j*9+4]);
      float dz = __fadd_rn(ciz, -xyz[j*9+5]);
      float Dv = sqrtf(__fadd_rn(__fadd_rn(__fadd_rn(__fmul_rn(dx,dx),
                         __fmul_rn(dy,dy)), __fmul_rn(dz,dz)), 1e-8f));
      kk = (((unsigned long long)__float_as_uint(Dv)) << 32) | (unsigned)j;
    }
    keys[j] = kk;
  }
  for (int size = 2; size <= 1024; size <<= 1) {
    for (int stride = size >> 1; stride > 0; stride >>= 1) {
      __syncthreads();
      for (int p = t; p < 512; p += 256) {
        int lo = 2*p - (p & (stride - 1));
        int hi = lo + stride;
        bool up = ((lo & size) == 0);
        unsigned long long a = keys[lo], b = keys[hi];
        if ((a > b) == up) { keys[lo] = b; keys[hi] = a; }
      }
    }
  }
  __syncthreads();
  if (t < TOPK) nbr[i*TOPK + t] = (int)(keys[t] & 0xffffffffu);
}

// ---------------- Kernel C1: edge0 (pre-LN) per selected edge --------------
__global__ __launch_bounds__(256) void kernC1(
    const float* __restrict__ pair, const float* __restrict__ xyz,
    const int* __restrict__ idx,
    const float* __restrict__ W_ee, const float* __restrict__ b_ee,
    const float* __restrict__ colsum_ee,
    const int* __restrict__ nbr, float* __restrict__ e0ws)
{
  const int i = blockIdx.x >> 1, part = blockIdx.x & 1;
  const int t = threadIdx.x, lane = t & 63, wv = t >> 6;
  const int slot = lane & 15, q = lane >> 4;     // q = 0..3 k-quarter
  const int p = part*64 + wv*16 + slot;          // neighbor slot 0..127

  const int j = nbr[i*TOPK + p];
  const float cix = xyz[i*9+3], ciy = xyz[i*9+4], ciz = xyz[i*9+5];
  const float dx = __fadd_rn(cix, -xyz[j*9+3]);
  const float dy = __fadd_rn(ciy, -xyz[j*9+4]);
  const float dz = __fadd_rn(ciz, -xyz[j*9+5]);
  const float Dv = sqrtf(__fadd_rn(__fadd_rn(__fadd_rn(__fmul_rn(dx,dx),
                      __fmul_rn(dy,dy)), __fmul_rn(dz,dz)), 1e-8f));

  const float* prow = pair + (((size_t)i*LL + j) * 128) + q*32;
  float acc[32];
#pragma unroll
  for (int c = 0; c < 32; ++c) acc[c] = 0.f;
  float s = 0.f, ss = 0.f;
#pragma unroll 2
  for (int q4 = 0; q4 < 8; ++q4) {
    float4 v = ((const float4*)prow)[q4];
    s  += (v.x + v.y) + (v.z + v.w);
    ss += v.x*v.x + v.y*v.y + v.z*v.z + v.w*v.w;
    const float* wr = W_ee + (q*32 + q4*4)*32;
    FMA_ROW32(acc, v.x, wr);
    FMA_ROW32(acc, v.y, wr + 32);
    FMA_ROW32(acc, v.z, wr + 64);
    FMA_ROW32(acc, v.w, wr + 96);
  }
  s  += __shfl_xor(s, 16);  s  += __shfl_xor(s, 32);
  ss += __shfl_xor(ss, 16); ss += __shfl_xor(ss, 32);
  const float pm  = s * (1.f/128.f);
  const float pvv = ss * (1.f/128.f) - pm*pm;
  const float prs = 1.f / sqrtf(pvv + 1e-5f);

#pragma unroll
  for (int c = 0; c < 32; ++c) acc[c] *= prs;

#pragma unroll 4
  for (int kk = 0; kk < 16; ++kk) {
    const int k = q*16 + kk;
    float mu = 2.f + (float)k * (20.f/63.f);
    float u  = (Dv - mu) / 0.3125f;
    FMA_ROW32(acc, expf(-(u*u)), W_ee + (128+k)*32);
  }
  if (q == 0) {
    const float offv = (float)(idx[j] - idx[i]);
    const float sg = (offv > 0.f) ? 1.f : ((offv < 0.f) ? -1.f : 0.f);
    const float xsep = sg * logf(fabsf(offv) + 1.f);
    FMA_ROW32(acc, xsep, W_ee + 192*32);
    const float corr = -prs * pm;
#pragma unroll
    for (int c = 0; c < 32; ++c) acc[c] += b_ee[c] + corr * colsum_ee[c];
  }
#pragma unroll
  for (int c = 0; c < 32; ++c) {
    acc[c] += __shfl_xor(acc[c], 16);
    acc[c] += __shfl_xor(acc[c], 32);
  }

  float4* e4 = (float4*)e0ws;
#pragma unroll
  for (int cc = 0; cc < 2; ++cc) {
    const int c4 = q*2 + cc;
    float4 w = make_float4(acc[c4*4], acc[c4*4+1], acc[c4*4+2], acc[c4*4+3]);
    e4[((size_t)i*8 + c4)*128 + p] = w;
  }
}

// ---------------- Kernel C2: edge MLP + message MLP + reduce ---------------
// thread (g = t>>3, q = t&7): 4 edges {g,g+32,g+64,g+96} x 8 channels [8q..)
// activations live in LDS (A: 32-wide, B: 64-wide); weights stream from L1.
__global__ __launch_bounds__(256) void kernC2(
    const float* __restrict__ xyz, const unsigned char* __restrict__ rmask,
    const float* __restrict__ We1, const float* __restrict__ be1,
    const float* __restrict__ We2, const float* __restrict__ be2,
    const float* __restrict__ Wm1, const float* __restrict__ bm1,
    const float* __restrict__ Wm2, const float* __restrict__ bm2,
    const float* __restrict__ Wl0, const float* __restrict__ bl0,
    const float* __restrict__ node, const int* __restrict__ nbr,
    const float* __restrict__ e0ws,
    float* __restrict__ soutf, float* __restrict__ out)
{
  const int i = blockIdx.x, t = threadIdx.x;
  const int g = t >> 3, q = t & 7;
  __shared__ float A[128][33];     // e0 -> ed -> e2 -> ed2 (in place)
  __shared__ float Bb[128][65];    // h -> m1 -> m2
  __shared__ float nd[128][33];    // neighbor node rows
  __shared__ float ni[32];
  __shared__ float relv[128][3];
  __shared__ float mA[128], sgA[128];
  __shared__ float P[44][32];      // per-g reduction partials
  __shared__ float fin[44];

  if (t < 32) ni[t] = node[i*32 + t];
  {  // stage neighbor node rows + rel
    const int pp = t >> 1, hh2 = t & 1;
    const int jj = nbr[i*TOPK + pp];
    const float4* nr = (const float4*)(node + jj*32 + hh2*16);
    float4 a0 = nr[0], a1 = nr[1], a2 = nr[2], a3 = nr[3];
    float* dst = &nd[pp][hh2*16];
    dst[0]=a0.x; dst[1]=a0.y; dst[2]=a0.z; dst[3]=a0.w;
    dst[4]=a1.x; dst[5]=a1.y; dst[6]=a1.z; dst[7]=a1.w;
    dst[8]=a2.x; dst[9]=a2.y; dst[10]=a2.z; dst[11]=a2.w;
    dst[12]=a3.x; dst[13]=a3.y; dst[14]=a3.z; dst[15]=a3.w;
    if (hh2 == 0) {
      relv[pp][0] = xyz[jj*9+3] - xyz[i*9+3];
      relv[pp][1] = xyz[jj*9+4] - xyz[i*9+4];
      relv[pp][2] = xyz[jj*9+5] - xyz[i*9+5];
    }
  }
  {  // stage e0 rows from C1 output
    const int p = t & 127, hh = t >> 7;
    const float4* src = (const float4*)e0ws + ((size_t)i*8 + hh*4)*128 + p;
#pragma unroll
    for (int n = 0; n < 4; ++n) {
      float4 v = src[(size_t)n*128];
      A[p][hh*16 + n*4 + 0] = v.x;
      A[p][hh*16 + n*4 + 1] = v.y;
      A[p][hh*16 + n*4 + 2] = v.z;
      A[p][hh*16 + n*4 + 3] = v.w;
    }
  }
  __syncthreads();

  // LN(A) in place; keep (mean, sigma) to recover raw e0 for the residual
  if (t < 128) {
    float mm = 0.f;
#pragma unroll
    for (int c = 0; c < 32; ++c) mm += A[t][c];
    mm *= (1.f/32.f);
    float vv = 0.f;
#pragma unroll
    for (int c = 0; c < 32; ++c) { float dd = A[t][c]-mm; vv += dd*dd; }
    vv *= (1.f/32.f);
    const float sg = sqrtf(vv + 1e-5f);
    const float rs = 1.f / sg;
#pragma unroll
    for (int c = 0; c < 32; ++c) A[t][c] = (A[t][c]-mm)*rs;
    mA[t] = mm; sgA[t] = sg;
  }
  __syncthreads();

  // ---- h = relu(ed @ We1 + be1): 4 edges x 8 ch per thread ----
  {
    float hacc[4][8];
#pragma unroll
    for (int m = 0; m < 4; ++m)
#pragma unroll
      for (int c = 0; c < 8; ++c) hacc[m][c] = 0.f;
#pragma unroll 4
    for (int k = 0; k < 32; ++k) {
      const float4 w0 = *(const float4*)(We1 + k*64 + q*8);
      const float4 w1 = *(const float4*)(We1 + k*64 + q*8 + 4);
      const float a0 = A[g][k], a1 = A[g+32][k], a2 = A[g+64][k], a3 = A[g+96][k];
#pragma unroll
      for (int m = 0; m < 4; ++m) {
        const float av = (m==0)?a0:(m==1)?a1:(m==2)?a2:a3;
        hacc[m][0] = fmaf(av, w0.x, hacc[m][0]);
        hacc[m][1] = fmaf(av, w0.y, hacc[m][1]);
        hacc[m][2] = fmaf(av, w0.z, hacc[m][2]);
        hacc[m][3] = fmaf(av, w0.w, hacc[m][3]);
        hacc[m][4] = fmaf(av, w1.x, hacc[m][4]);
        hacc[m][5] = fmaf(av, w1.y, hacc[m][5]);
        hacc[m][6] = fmaf(av, w1.z, hacc[m][6]);
        hacc[m][7] = fmaf(av, w1.w, hacc[m][7]);
      }
    }
#pragma unroll
    for (int m = 0; m < 4; ++m) {
      const int e = g + 32*m;
#pragma unroll
      for (int c = 0; c < 8; ++c)
        Bb[e][8*q + c] = fmaxf(hacc[m][c] + be1[8*q + c], 0.f);
    }
  }
  __syncthreads();

  // ---- e2 = e0raw + h @ We2 + be2: 4 edges x 4 ch per thread ----
  {
    float e2a[4][4];
#pragma unroll
    for (int m = 0; m < 4; ++m)
#pragma unroll
      for (int c = 0; c < 4; ++c) e2a[m][c] = 0.f;
#pragma unroll 4
    for (int k = 0; k < 64; ++k) {
      const float4 w = *(const float4*)(We2 + k*32 + q*4);
      const float a0 = Bb[g][k], a1 = Bb[g+32][k], a2 = Bb[g+64][k], a3 = Bb[g+96][k];
#pragma unroll
      for (int m = 0; m < 4; ++m) {
        const float av = (m==0)?a0:(m==1)?a1:(m==2)?a2:a3;
        e2a[m][0] = fmaf(av, w.x, e2a[m][0]);
        e2a[m][1] = fmaf(av, w.y, e2a[m][1]);
        e2a[m][2] = fmaf(av, w.z, e2a[m][2]);
        e2a[m][3] = fmaf(av, w.w, e2a[m][3]);
      }
    }
#pragma unroll
    for (int m = 0; m < 4; ++m) {
      const int e = g + 32*m;
      const float sg = sgA[e], mm = mA[e];
#pragma unroll
      for (int c = 0; c < 4; ++c) {
        const int ch = 4*q + c;
        const float e0raw = fmaf(A[e][ch], sg, mm);   // undo LN
        A[e][ch] = e2a[m][c] + e0raw + be2[ch];
      }
    }
  }
  __syncthreads();

  // LN(e2) in place (stats not needed afterwards)
  if (t < 128) {
    float mm = 0.f;
#pragma unroll
    for (int c = 0; c < 32; ++c) mm += A[t][c];
    mm *= (1.f/32.f);
    float vv = 0.f;
#pragma unroll
    for (int c = 0; c < 32; ++c) { float dd = A[t][c]-mm; vv += dd*dd; }
    vv *= (1.f/32.f);
    const float rs = 1.f / sqrtf(vv + 1e-5f);
#pragma unroll
    for (int c = 0; c < 32; ++c) A[t][c] = (A[t][c]-mm)*rs;
  }
  __syncthreads();

  // ---- m1 = relu([ni, nj, ed2] @ Wm1 + bm1): 4 edges x 8 ch per thread ----
  {
    float tmp[8];   // ni part — identical for all edges, compute once
#pragma unroll
    for (int c = 0; c < 8; ++c) tmp[c] = bm1[8*q + c];
#pragma unroll 4
    for (int k = 0; k < 32; ++k) {
      const float4 w0 = *(const float4*)(Wm1 + k*64 + q*8);
      const float4 w1 = *(const float4*)(Wm1 + k*64 + q*8 + 4);
      const float av = ni[k];
      tmp[0] = fmaf(av, w0.x, tmp[0]); tmp[1] = fmaf(av, w0.y, tmp[1]);
      tmp[2] = fmaf(av, w0.z, tmp[2]); tmp[3] = fmaf(av, w0.w, tmp[3]);
      tmp[4] = fmaf(av, w1.x, tmp[4]); tmp[5] = fmaf(av, w1.y, tmp[5]);
      tmp[6] = fmaf(av, w1.z, tmp[6]); tmp[7] = fmaf(av, w1.w, tmp[7]);
    }
    float macc[4][8];
#pragma unroll
    for (int m = 0; m < 4; ++m)
#pragma unroll
      for (int c = 0; c < 8; ++c) macc[m][c] = 0.f;
#pragma unroll 4
    for (int k = 0; k < 32; ++k) {  // h_j part
      const float4 w0 = *(const float4*)(Wm1 + (32+k)*64 + q*8);
      const float4 w1 = *(const float4*)(Wm1 + (32+k)*64 + q*8 + 4);
      const float a0 = nd[g][k], a1 = nd[g+32][k], a2 = nd[g+64][k], a3 = nd[g+96][k];
#pragma unroll
      for (int m = 0; m < 4; ++m) {
        const float av = (m==0)?a0:(m==1)?a1:(m==2)?a2:a3;
        macc[m][0] = fmaf(av, w0.x, macc[m][0]);
        macc[m][1] = fmaf(av, w0.y, macc[m][1]);
        macc[m][2] = fmaf(av, w0.z, macc[m][2]);
        macc[m][3] = fmaf(av, w0.w, macc[m][3]);
        macc[m][4] = fmaf(av, w1.x, macc[m][4]);
        macc[m][5] = fmaf(av, w1.y, macc[m][5]);
        macc[m][6] = fmaf(av, w1.z, macc[m][6]);
        macc[m][7] = fmaf(av, w1.w, macc[m][7]);
      }
    }
#pragma unroll 4
    for (int k = 0; k < 32; ++k) {  // edge part
      const float4 w0 = *(const float4*)(Wm1 + (64+k)*64 + q*8);
      const float4 w1 = *(const float4*)(Wm1 + (64+k)*64 + q*8 + 4);
      const float a0 = A[g][k], a1 = A[g+32][k], a2 = A[g+64][k], a3 = A[g+96][k];
#pragma unroll
      for (int m = 0; m < 4; ++m) {
        const float av = (m==0)?a0:(m==1)?a1:(m==2)?a2:a3;
        macc[m][0] = fmaf(av, w0.x, macc[m][0]);
        macc[m][1] = fmaf(av, w0.y, macc[m][1]);
        macc[m][2] = fmaf(av, w0.z, macc[m][2]);
        macc[m][3] = fmaf(av, w0.w, macc[m][3]);
        macc[m][4] = fmaf(av, w1.x, macc[m][4]);
        macc[m][5] = fmaf(av, w1.y, macc[m][5]);
        macc[m][6] = fmaf(av, w1.z, macc[m][6]);
        macc[m][7] = fmaf(av, w1.w, macc[m][7]);
      }
    }
    __syncthreads();   // all A/nd reads done before Bb overwrite
#pragma unroll
    for (int m = 0; m < 4; ++m) {
      const int e = g + 32*m;
#pragma unroll
      for (int c = 0; c < 8; ++c)
        Bb[e][8*q + c] = fmaxf(macc[m][c] + tmp[c], 0.f);
    }
  }
  __syncthreads();

  // ---- m2 partial: 4 edges x 5 outputs per thread; expand + reduce ----
  {
    float p2[4][5];
#pragma unroll
    for (int m = 0; m < 4; ++m)
#pragma unroll
      for (int o = 0; o < 5; ++o) p2[m][o] = 0.f;
#pragma unroll 4
    for (int k = 0; k < 64; ++k) {
      const float* wr = Wm2 + k*40 + 5*q;
      const float w0 = wr[0], w1 = wr[1], w2 = wr[2], w3 = wr[3], w4 = wr[4];
      const float a0 = Bb[g][k], a1 = Bb[g+32][k], a2 = Bb[g+64][k], a3 = Bb[g+96][k];
#pragma unroll
      for (int m = 0; m < 4; ++m) {
        const float av = (m==0)?a0:(m==1)?a1:(m==2)?a2:a3;
        p2[m][0] = fmaf(av, w0, p2[m][0]);
        p2[m][1] = fmaf(av, w1, p2[m][1]);
        p2[m][2] = fmaf(av, w2, p2[m][2]);
        p2[m][3] = fmaf(av, w3, p2[m][3]);
        p2[m][4] = fmaf(av, w4, p2[m][4]);
      }
    }
    const float b0 = bm2[5*q], b1 = bm2[5*q+1], b2 = bm2[5*q+2],
                b3 = bm2[5*q+3], b4 = bm2[5*q+4];
    float outv[9];
#pragma unroll
    for (int s = 0; s < 9; ++s) outv[s] = 0.f;
#pragma unroll
    for (int m = 0; m < 4; ++m) {
      const int e = g + 32*m;
      const float v0 = p2[m][0]+b0, v1 = p2[m][1]+b1, v2 = p2[m][2]+b2,
                  v3 = p2[m][3]+b3, v4 = p2[m][4]+b4;
      if (q == 6) {   // o=30,31 plain; o=32,33 x rel; o=34 plain
        outv[0] += v0; outv[1] += v1;
        outv[2] = fmaf(v2, relv[e][0], outv[2]);
        outv[3] = fmaf(v2, relv[e][1], outv[3]);
        outv[4] = fmaf(v2, relv[e][2], outv[4]);
        outv[5] = fmaf(v3, relv[e][0], outv[5]);
        outv[6] = fmaf(v3, relv[e][1], outv[6]);
        outv[7] = fmaf(v3, relv[e][2], outv[7]);
        outv[8] += v4;
      } else {
        outv[0] += v0; outv[1] += v1; outv[2] += v2; outv[3] += v3; outv[4] += v4;
      }
    }
    if (q == 6) {
#pragma unroll
      for (int s = 0; s < 9; ++s) P[30 + s][g] = outv[s];
    } else {
      const int base = (q == 7) ? 39 : 5*q;
#pragma unroll
      for (int s = 0; s < 5; ++s) P[base + s][g] = outv[s];
    }
  }
  __syncthreads();

  if (t < 44) {
    float sum = 0.f;
#pragma unroll
    for (int gg = 0; gg < 32; ++gg) sum += P[t][gg];
    fin[t] = sum;
  }
  __syncthreads();

  if (t < 16) {  // state_out = [node_i, m_l0] @ Wl0 + bl0
    float a = bl0[t];
#pragma unroll
    for (int k = 0; k < 32; ++k) a = fmaf(ni[k], Wl0[k*16 + t], a);
#pragma unroll
    for (int k = 0; k < 32; ++k) a = fmaf(fin[k] * (1.f/128.f), Wl0[(32+k)*16 + t], a);
    soutf[i*16 + t] = a;
    out[LL*9 + i*16 + t] = a;
  }
  if (t == 0) {  // frame update
    float ve[6], wa[6];
#pragma unroll
    for (int qq = 0; qq < 6; ++qq) ve[qq] = fin[32 + qq] * (1.f/128.f);
#pragma unroll
    for (int qq = 0; qq < 6; ++qq) wa[qq] = fin[38 + qq] * (1.f/128.f);
    float l1[9];
#pragma unroll
    for (int a = 0; a < 3; ++a)
#pragma unroll
      for (int d = 0; d < 3; ++d) l1[a*3 + d] = xyz[i*9 + a*3 + d] - xyz[i*9 + 3 + d];
    float T[3], Rv[3];
#pragma unroll
    for (int d = 0; d < 3; ++d) {
      float va0 = wa[0]*l1[d] + wa[1]*l1[3 + d] + wa[2]*l1[6 + d];
      float va1 = wa[3]*l1[d] + wa[4]*l1[3 + d] + wa[5]*l1[6 + d];
      T[d]  = (ve[d] + va0) / 10.f;
      Rv[d] = (ve[3 + d] + va1) / 100.f;
    }
    float qn = sqrtf(1.f + Rv[0]*Rv[0] + Rv[1]*Rv[1] + Rv[2]*Rv[2]);
    float qA = 1.f/qn, qB = Rv[0]/qn, qC = Rv[1]/qn, qD = Rv[2]/qn;
    float Rm[9];
    Rm[0] = qA*qA + qB*qB - qC*qC - qD*qD;
    Rm[1] = 2.f*qB*qC - 2.f*qA*qD;
    Rm[2] = 2.f*qB*qD + 2.f*qA*qC;
    Rm[3] = 2.f*qB*qC + 2.f*qA*qD;
    Rm[4] = qA*qA - qB*qB + qC*qC - qD*qD;
    Rm[5] = 2.f*qC*qD - 2.f*qA*qB;
    Rm[6] = 2.f*qB*qD - 2.f*qA*qC;
    Rm[7] = 2.f*qC*qD + 2.f*qA*qB;
    Rm[8] = qA*qA - qB*qB - qC*qC + qD*qD;
    if (rmask[i]) {
      Rm[0] = 1.f; Rm[1] = 0.f; Rm[2] = 0.f;
      Rm[3] = 0.f; Rm[4] = 1.f; Rm[5] = 0.f;
      Rm[6] = 0.f; Rm[7] = 0.f; Rm[8] = 1.f;
    }
#pragma unroll
    for (int a = 0; a < 3; ++a)
#pragma unroll
      for (int di = 0; di < 3; ++di) {
        float xn = Rm[di*3+0]*l1[a*3+0] + Rm[di*3+1]*l1[a*3+1] + Rm[di*3+2]*l1[a*3+2]
                 + xyz[i*9 + 3 + di] + T[di];
        out[i*9 + a*3 + di] = xn;
      }
  }
}

// ---------------- Kernel D: si MLP stack -> alpha ---------------------------
__global__ __launch_bounds__(128) void kernD(
    const float* __restrict__ seq_ln, const float* __restrict__ st_out,
    const float* __restrict__ Ws0, const float* __restrict__ bs0,
    const float* __restrict__ Wsi, const float* __restrict__ bsi,
    const float* __restrict__ Wp1, const float* __restrict__ bp1,
    const float* __restrict__ Wp2, const float* __restrict__ bp2,
    const float* __restrict__ Wp3, const float* __restrict__ bp3,
    const float* __restrict__ Wp4, const float* __restrict__ bp4,
    const float* __restrict__ Wout, const float* __restrict__ bout,
    float* __restrict__ out)
{
  const int i = blockIdx.x, t = threadIdx.x;
  __shared__ float x0[256], stn[16], ra[128], ga[128], rb[128], gb[128], rc[128];
  x0[t]       = seq_ln[i*256 + t];
  x0[128 + t] = seq_ln[i*256 + 128 + t];
  if (t < 16) {
    float m = 0.f;
    for (int k = 0; k < 16; ++k) m += st_out[i*16 + k];
    m *= (1.f/16.f);
    float v = 0.f;
    for (int k = 0; k < 16; ++k) { float dd = st_out[i*16 + k] - m; v += dd*dd; }
    v *= (1.f/16.f);
    stn[t] = (st_out[i*16 + t] - m) / sqrtf(v + 1e-5f);
  }
  __syncthreads();

  float si = bs0[t] + bsi[t];
  for (int k = 0; k < 256; ++k) si = fmaf(x0[k], Ws0[k*128 + t], si);
  for (int k = 0; k < 16; ++k)  si = fmaf(stn[k], Wsi[k*128 + t], si);
  ra[t] = fmaxf(si, 0.f);
  __syncthreads();
  float h = bp1[t];
  for (int k = 0; k < 128; ++k) h = fmaf(ra[k], Wp1[k*128 + t], h);
  ga[t] = fmaxf(h, 0.f);
  __syncthreads();
  float d2 = bp2[t];
  for (int k = 0; k < 128; ++k) d2 = fmaf(ga[k], Wp2[k*128 + t], d2);
  si += d2;
  rb[t] = fmaxf(si, 0.f);
  __syncthreads();
  float h2 = bp3[t];
  for (int k = 0; k < 128; ++k) h2 = fmaf(rb[k], Wp3[k*128 + t], h2);
  gb[t] = fmaxf(h2, 0.f);
  __syncthreads();
  float d4 = bp4[t];
  for (int k = 0; k < 128; ++k) d4 = fmaf(gb[k], Wp4[k*128 + t], d4);
  si += d4;
  rc[t] = fmaxf(si, 0.f);
  __syncthreads();
  if (t < 20) {
    float a = bout[t];
    for (int k = 0; k < 128; ++k) a = fmaf(rc[k], Wout[k*20 + t], a);
    out[19200 + i*20 + t] = a;
  }
}

extern "C" void kernel_launch(void* const* d_in, const int* in_sizes, int n_in,
                              void* d_out, int out_size, void* d_ws, size_t ws_size,
                              hipStream_t stream)
{
  (void)in_sizes; (void)n_in; (void)out_size; (void)ws_size;
  const float* msa   = (const float*)d_in[0];
  const float* pair  = (const float*)d_in[1];
  const float* xyz   = (const float*)d_in[2];
  const float* state = (const float*)d_in[3];
  const int*   idx   = (const int*)d_in[4];
  const unsigned char* rmask = (const unsigned char*)d_in[5];
  const float* W_en = (const float*)d_in[6];
  const float* b_en = (const float*)d_in[7];
  const float* Wn1  = (const float*)d_in[8];
  const float* bn1  = (const float*)d_in[9];
  const float* Wn2  = (const float*)d_in[10];
  const float* bn2  = (const float*)d_in[11];
  const float* W_ee = (const float*)d_in[12];
  const float* b_ee = (const float*)d_in[13];
  const float* We1  = (const float*)d_in[14];
  const float* be1  = (const float*)d_in[15];
  const float* We2  = (const float*)d_in[16];
  const float* be2  = (const float*)d_in[17];
  const float* Wm1  = (const float*)d_in[18];
  const float* bm1  = (const float*)d_in[19];
  const float* Wm2  = (const float*)d_in[20];
  const float* bm2  = (const float*)d_in[21];
  const float* Wl0  = (const float*)d_in[22];
  const float* bl0  = (const float*)d_in[23];
  const float* Ws0  = (const float*)d_in[24];
  const float* bs0  = (const float*)d_in[25];
  const float* Wsi  = (const float*)d_in[26];
  const float* bsi  = (const float*)d_in[27];
  const float* Wp1  = (const float*)d_in[28];
  const float* bp1  = (const float*)d_in[29];
  const float* Wp2  = (const float*)d_in[30];
  const float* bp2  = (const float*)d_in[31];
  const float* Wp3  = (const float*)d_in[32];
  const float* bp3  = (const float*)d_in[33];
  const float* Wp4  = (const float*)d_in[34];
  const float* bp4  = (const float*)d_in[35];
  const float* Wout = (const float*)d_in[36];
  const float* bout = (const float*)d_in[37];

  float* wsf    = (float*)d_ws;
  float* seq_ln = wsf + WS_SEQ;
  float* nodev  = wsf + WS_NODE;
  int*   nbr    = (int*)(wsf + WS_NBR);
  float* soutf  = wsf + WS_SOUT;
  float* csee   = wsf + WS_CSEE;
  float* e0ws   = wsf + WS_E0;
  float* out = (float*)d_out;

  kernP<<<1, 32, 0, stream>>>(W_ee, csee);
  kernA<<<LL, 256, 0, stream>>>(msa, state, W_en, b_en, Wn1, bn1, Wn2, bn2, seq_ln, nodev);
  kernB<<<LL, 256, 0, stream>>>(xyz, nbr);
  kernC1<<<LL*2, 256, 0, stream>>>(pair, xyz, idx, W_ee, b_ee, csee, nbr, e0ws);
  kernC2<<<LL, 256, 0, stream>>>(xyz, rmask, We1, be1, We2, be2, Wm1, bm1, Wm2, bm2,
                                 Wl0, bl0, nodev, nbr, e0ws, soutf, out);
  kernD<<<LL, 128, 0, stream>>>(seq_ln, soutf, Ws0, bs0, Wsi, bsi, Wp1, bp1, Wp2, bp2,
                                Wp3, bp3, Wp4, bp4, Wout, bout, out);
}